// Round 5
// baseline (503.595 us; speedup 1.0000x reference)
//
#include <hip/hip_runtime.h>
#include <stdint.h>

#define V 8192
#define C 128
#define BK 64
#define NT (V / BK)   // 128 k-tiles: full-K sweep per block

typedef __attribute__((ext_vector_type(8))) short short8;
typedef __attribute__((ext_vector_type(4))) float floatx4;

static __device__ __forceinline__ unsigned short f2bf(float f) {
    unsigned u = __float_as_uint(f);
    u += 0x7FFF + ((u >> 16) & 1);   // RNE
    return (unsigned short)(u >> 16);
}

// async global->LDS, 16B per lane; LDS dest is wave-uniform base + lane*16
static __device__ __forceinline__ void gload16(const void* g, void* l) {
    __builtin_amdgcn_global_load_lds(
        (const __attribute__((address_space(1))) void*)g,
        (__attribute__((address_space(3))) void*)l, 16, 0, 0);
}
#define SWAIT(s) asm volatile("s_waitcnt " s ::: "memory")
#define SBAR() __builtin_amdgcn_s_barrier()
#define SFENCE() __builtin_amdgcn_sched_barrier(0)

// ---------------------------------------------------------------- prep
// XMT[c][k] = bf16(x[k][c] * mass[k]); 64x64 LDS tiled transpose
__global__ __launch_bounds__(256) void prep_xmt(const float* __restrict__ x,
                                                const float* __restrict__ mass,
                                                unsigned short* __restrict__ XMT) {
    __shared__ float tile[64][65];
    const int k0 = blockIdx.x * 64;
    const int c0 = blockIdx.y * 64;
    const int t = threadIdx.x;
#pragma unroll
    for (int p = 0; p < 16; ++p) {
        int idx = p * 256 + t;
        int kk = idx >> 6, cc = idx & 63;
        tile[kk][cc] = x[(size_t)(k0 + kk) * C + (c0 + cc)] * mass[k0 + kk];
    }
    __syncthreads();
#pragma unroll
    for (int p = 0; p < 16; ++p) {
        int idx = p * 256 + t;
        int cc = idx >> 6, kk = idx & 63;
        XMT[(size_t)(c0 + cc) * V + (k0 + kk)] = f2bf(tile[kk][cc]);
    }
}

// ---------------------------------------------------------------- GEMM1+coef
// YT[c][j] = bf16( coef(c,j) * sum_v XMT[c][v] * E[v][j] ), j-slab of 32/block.
// Full K=8192 sweep -> no P1 intermediate, no red1. E read exactly once.
// A = XMT (L2-hot) via global_load_lds; B = fp32 E slab, reg->bf16->LDS
// (2 staging waves), both double-buffered; counted vmcnt keeps E prefetch alive.
__global__ __launch_bounds__(512, 2) void gemm1y(const unsigned short* __restrict__ XMT,
                                                 const float* __restrict__ E,
                                                 const float* __restrict__ ev0,
                                                 const float* __restrict__ ev1,
                                                 const float* __restrict__ dt,
                                                 unsigned short* __restrict__ YT) {
    __shared__ __align__(16) unsigned short ldsA[2][128 * BK];  // 32 KB
    __shared__ __align__(16) unsigned short ldsB[2][32 * BK];   // 8 KB
    const int j0 = blockIdx.x * 32;
    const int t = threadIdx.x;
    const int w = t >> 6, lane = t & 63, q = lane >> 4, l15 = lane & 15;
    const int wr = w >> 1, wc = w & 1;          // wave tile: rows wr*32, cols wc*16
    const int lr = lane >> 3, lch = (lane & 7) ^ lr;
    const int vq4 = t >> 3;                     // B staging (t<128): rows vq4*4..+3
    const int jgc = t & 7;                      // B staging: j-chunk (4 cols)

    floatx4 acc[2] = {};
    float4 er0[4], er1[4];

#define G1_GLOADA(TI, BUF)                                                          \
    {                                                                               \
        const int kk_ = (TI) * BK;                                                  \
        _Pragma("unroll")                                                           \
        for (int i = 0; i < 2; ++i)                                                 \
            gload16(&XMT[(size_t)(i * 64 + w * 8 + lr) * V + kk_ + 8 * lch],        \
                    &ldsA[BUF][i * 4096 + w * 512]);                                \
    }
#define G1_ELOAD(ER, TI)                                                            \
    if (w < 2) {                                                                    \
        const int kk_ = (TI) * BK;                                                  \
        _Pragma("unroll")                                                           \
        for (int u = 0; u < 4; ++u)                                                 \
            ER[u] = *(const float4*)&E[(size_t)(kk_ + vq4 * 4 + u) * V + j0 + jgc * 4]; \
    }
#define G1_CONV(ER, BUF)                                                            \
    if (w < 2) {                                                                    \
        _Pragma("unroll")                                                           \
        for (int jj = 0; jj < 4; ++jj) {                                            \
            const int j = jgc * 4 + jj;                                             \
            ushort4 b;                                                              \
            b.x = f2bf(ER[0][jj]); b.y = f2bf(ER[1][jj]);                           \
            b.z = f2bf(ER[2][jj]); b.w = f2bf(ER[3][jj]);                           \
            *(ushort4*)&ldsB[BUF][j * BK + ((vq4 >> 1) ^ (j & 7)) * 8 + (vq4 & 1) * 4] = b; \
        }                                                                           \
    }
#define G1_MFMA(pA, pB)                                                             \
    {                                                                               \
        _Pragma("unroll")                                                           \
        for (int kk = 0; kk < BK; kk += 32) {                                       \
            short8 af[2], bf1;                                                      \
            _Pragma("unroll")                                                       \
            for (int mi = 0; mi < 2; ++mi) {                                        \
                const int m = wr * 32 + mi * 16 + l15;                              \
                af[mi] = *(const short8*)&pA[m * BK + 8 * (((kk >> 3) + q) ^ (m & 7))]; \
            }                                                                       \
            {                                                                       \
                const int n = wc * 16 + l15;                                        \
                bf1 = *(const short8*)&pB[n * BK + 8 * (((kk >> 3) + q) ^ (n & 7))]; \
            }                                                                       \
            _Pragma("unroll")                                                       \
            for (int mi = 0; mi < 2; ++mi)                                          \
                acc[mi] = __builtin_amdgcn_mfma_f32_16x16x32_bf16(af[mi], bf1, acc[mi], 0, 0, 0); \
        }                                                                           \
    }
#define G1_WAITBAR()                                                                \
    {                                                                               \
        if (w < 2) { SWAIT("vmcnt(4) lgkmcnt(0)"); } else { SWAIT("vmcnt(0) lgkmcnt(0)"); } \
        SBAR();                                                                     \
        SFENCE();                                                                   \
    }

    // prologue: tile 0 staged, E(1) in regs
    G1_ELOAD(er0, 0);
    G1_GLOADA(0, 0);
    G1_ELOAD(er1, 1);
    G1_CONV(er0, 0);
    G1_WAITBAR();

#define G1_BODY(T, PF_ER, CV_ER)                                                    \
    {                                                                               \
        const int t1 = (T) + 1;                                                     \
        const int t2 = ((T) + 2 < NT) ? (T) + 2 : NT - 1;                           \
        const bool pf = t1 < NT;                                                    \
        if (pf) {                                                                   \
            G1_GLOADA(t1, cur ^ 1);                                                 \
            G1_ELOAD(PF_ER, t2);                                                    \
        }                                                                           \
        SFENCE();                                                                   \
        __builtin_amdgcn_s_setprio(1);                                              \
        G1_MFMA((&ldsA[cur][0]), (&ldsB[cur][0]));                                  \
        __builtin_amdgcn_s_setprio(0);                                              \
        SFENCE();                                                                   \
        if (pf) {                                                                   \
            G1_CONV(CV_ER, cur ^ 1);                                                \
            G1_WAITBAR();                                                           \
            cur ^= 1;                                                               \
        }                                                                           \
    }

    int cur = 0;
    for (int tt = 0; tt < NT; tt += 2) {
        G1_BODY(tt, er0, er1);
        G1_BODY(tt + 1, er1, er0);
    }
#undef G1_BODY
#undef G1_WAITBAR
#undef G1_MFMA
#undef G1_CONV
#undef G1_ELOAD
#undef G1_GLOADA

    // epilogue: coef = exp(-(ev0[j>>7]*t0[c] + ev1[j&127]*t1[c])), write YT
    const int jg_ = j0 + wc * 16 + l15;
    const float a0 = ev0[j0 >> 7];          // block-constant (32-slab within 128)
    const float e1j = ev1[jg_ & 127];
#pragma unroll
    for (int mi = 0; mi < 2; ++mi) {
#pragma unroll
        for (int r = 0; r < 4; ++r) {
            const int c = wr * 32 + mi * 16 + q * 4 + r;
            const float coef = __expf(-(a0 * dt[c] + e1j * dt[C + c]));
            YT[(size_t)c * V + jg_] = f2bf(acc[mi][r] * coef);
        }
    }
}

// ---------------------------------------------------------------- GEMM2
// out[i][c] = sum_j E[i][j] * YT[c][j], i-slab of 32/block, full K=8192.
// No P2 intermediate, no red2. E rows read exactly once (coalesced 256B).
// A = fp32 E rows reg->bf16->LDS (all threads, 1 float4 each); B = YT (L2-hot)
// via global_load_lds.
__global__ __launch_bounds__(512, 2) void gemm2o(const float* __restrict__ E,
                                                 const unsigned short* __restrict__ YT,
                                                 float* __restrict__ out) {
    __shared__ __align__(16) unsigned short ldsA[2][32 * BK];   // 8 KB
    __shared__ __align__(16) unsigned short ldsB[2][128 * BK];  // 32 KB
    const int i0 = blockIdx.x * 32;
    const int t = threadIdx.x;
    const int w = t >> 6, lane = t & 63, q = lane >> 4, l15 = lane & 15;
    const int wr = w >> 2, wc = w & 3;          // wave tile: rows wr*16, cols wc*32
    const int lr = lane >> 3, lch = (lane & 7) ^ lr;
    const int arow = t >> 4;                    // A staging: row 0..31
    const int ach = t & 15;                     // A staging: 16B chunk in 256B row

    floatx4 acc[2] = {};
    float4 er0, er1;

#define G2_GLOADB(TI, BUF)                                                          \
    {                                                                               \
        const int kk_ = (TI) * BK;                                                  \
        _Pragma("unroll")                                                           \
        for (int i = 0; i < 2; ++i)                                                 \
            gload16(&YT[(size_t)(i * 64 + w * 8 + lr) * V + kk_ + 8 * lch],         \
                    &ldsB[BUF][i * 4096 + w * 512]);                                \
    }
#define G2_ELOAD(ER, TI)                                                            \
    {                                                                               \
        const int kk_ = (TI) * BK;                                                  \
        ER = *(const float4*)&E[(size_t)(i0 + arow) * V + kk_ + ach * 4];           \
    }
#define G2_CONV(ER, BUF)                                                            \
    {                                                                               \
        ushort4 av;                                                                 \
        av.x = f2bf(ER.x); av.y = f2bf(ER.y); av.z = f2bf(ER.z); av.w = f2bf(ER.w); \
        *(ushort4*)&ldsA[BUF][arow * BK + ((ach >> 1) ^ (arow & 7)) * 8 + (ach & 1) * 4] = av; \
    }
#define G2_MFMA(pA, pB)                                                             \
    {                                                                               \
        _Pragma("unroll")                                                           \
        for (int kk = 0; kk < BK; kk += 32) {                                       \
            short8 af1, bf[2];                                                      \
            {                                                                       \
                const int m = wr * 16 + l15;                                        \
                af1 = *(const short8*)&pA[m * BK + 8 * (((kk >> 3) + q) ^ (m & 7))]; \
            }                                                                       \
            _Pragma("unroll")                                                       \
            for (int ni = 0; ni < 2; ++ni) {                                        \
                const int n = wc * 32 + ni * 16 + l15;                              \
                bf[ni] = *(const short8*)&pB[n * BK + 8 * (((kk >> 3) + q) ^ (n & 7))]; \
            }                                                                       \
            _Pragma("unroll")                                                       \
            for (int ni = 0; ni < 2; ++ni)                                          \
                acc[ni] = __builtin_amdgcn_mfma_f32_16x16x32_bf16(af1, bf[ni], acc[ni], 0, 0, 0); \
        }                                                                           \
    }

    // prologue
    G2_ELOAD(er0, 0);
    G2_GLOADB(0, 0);
    G2_ELOAD(er1, 1);
    G2_CONV(er0, 0);
    SWAIT("vmcnt(1) lgkmcnt(0)");   // retire gloads; er1 rides
    SBAR();
    SFENCE();

#define G2_BODY(T, PF_ER, CV_ER)                                                    \
    {                                                                               \
        const int t1 = (T) + 1;                                                     \
        const int t2 = ((T) + 2 < NT) ? (T) + 2 : NT - 1;                           \
        const bool pf = t1 < NT;                                                    \
        if (pf) {                                                                   \
            G2_GLOADB(t1, cur ^ 1);                                                 \
            G2_ELOAD(PF_ER, t2);                                                    \
        }                                                                           \
        SFENCE();                                                                   \
        __builtin_amdgcn_s_setprio(1);                                              \
        G2_MFMA((&ldsA[cur][0]), (&ldsB[cur][0]));                                  \
        __builtin_amdgcn_s_setprio(0);                                              \
        SFENCE();                                                                   \
        if (pf) {                                                                   \
            G2_CONV(CV_ER, cur ^ 1);                                                \
            SWAIT("vmcnt(1) lgkmcnt(0)");                                           \
            SBAR();                                                                 \
            SFENCE();                                                               \
            cur ^= 1;                                                               \
        }                                                                           \
    }

    int cur = 0;
    for (int tt = 0; tt < NT; tt += 2) {
        G2_BODY(tt, er0, er1);
        G2_BODY(tt + 1, er1, er0);
    }
#undef G2_BODY
#undef G2_MFMA
#undef G2_CONV
#undef G2_ELOAD
#undef G2_GLOADB

    // epilogue: direct fp32 store (64B segments per 16 lanes)
#pragma unroll
    for (int ni = 0; ni < 2; ++ni) {
#pragma unroll
        for (int r = 0; r < 4; ++r)
            out[(size_t)(i0 + wr * 16 + q * 4 + r) * C + wc * 32 + ni * 16 + l15] =
                acc[ni][r];
    }
}

// ---------------------------------------------------------------- launch
extern "C" void kernel_launch(void* const* d_in, const int* in_sizes, int n_in,
                              void* d_out, int out_size, void* d_ws, size_t ws_size,
                              hipStream_t stream) {
    const float* x    = (const float*)d_in[0];
    const float* mass = (const float*)d_in[3];
    const float* ev0  = (const float*)d_in[4];
    const float* ev1  = (const float*)d_in[5];
    const float* E    = (const float*)d_in[6];
    const float* dt   = (const float*)d_in[7];
    float* out = (float*)d_out;

    // ws: XMT (2 MB) | YT (2 MB)
    unsigned short* XMT = (unsigned short*)d_ws;
    unsigned short* YT  = XMT + (size_t)V * C;

    prep_xmt<<<dim3(V / 64, C / 64), 256, 0, stream>>>(x, mass, XMT);
    gemm1y<<<V / 32, 512, 0, stream>>>(XMT, E, ev0, ev1, dt, YT);
    gemm2o<<<V / 32, 512, 0, stream>>>(E, YT, out);
}

// Round 6
// 443.294 us; speedup vs baseline: 1.1360x; 1.1360x over previous
//
#include <hip/hip_runtime.h>
#include <stdint.h>

#define V 8192
#define C 128
#define KS 4
#define KCH (V / KS)   // 2048
#define BK 64
#define NI (KCH / BK)  // 32 k-tiles per chunk

typedef __attribute__((ext_vector_type(8))) short short8;
typedef __attribute__((ext_vector_type(4))) float floatx4;

static __device__ __forceinline__ unsigned short f2bf(float f) {
    unsigned u = __float_as_uint(f);
    u += 0x7FFF + ((u >> 16) & 1);   // RNE
    return (unsigned short)(u >> 16);
}

// async global->LDS, 16B per lane; LDS dest is wave-uniform base + lane*16
static __device__ __forceinline__ void gload16(const void* g, void* l) {
    __builtin_amdgcn_global_load_lds(
        (const __attribute__((address_space(1))) void*)g,
        (__attribute__((address_space(3))) void*)l, 16, 0, 0);
}
#define SWAIT(s) asm volatile("s_waitcnt " s ::: "memory")
#define SBAR() __builtin_amdgcn_s_barrier()
#define SFENCE() __builtin_amdgcn_sched_barrier(0)

// ---------------------------------------------------------------- prep
// XMT[c][k] = bf16(x[k][c] * mass[k]); 64x64 LDS tiled transpose
__global__ __launch_bounds__(256) void prep_xmt(const float* __restrict__ x,
                                                const float* __restrict__ mass,
                                                unsigned short* __restrict__ XMT) {
    __shared__ float tile[64][65];
    const int k0 = blockIdx.x * 64;
    const int c0 = blockIdx.y * 64;
    const int t = threadIdx.x;
#pragma unroll
    for (int p = 0; p < 16; ++p) {
        int idx = p * 256 + t;
        int kk = idx >> 6, cc = idx & 63;
        tile[kk][cc] = x[(size_t)(k0 + kk) * C + (c0 + cc)] * mass[k0 + kk];
    }
    __syncthreads();
#pragma unroll
    for (int p = 0; p < 16; ++p) {
        int idx = p * 256 + t;
        int cc = idx >> 6, kk = idx & 63;
        XMT[(size_t)(c0 + cc) * V + (k0 + kk)] = f2bf(tile[kk][cc]);
    }
}

// ---------------------------------------------------------------- GEMM1
// P1[ks][c][j] = sum_{v in chunk ks} XMT[c][v] * E[v][j]
// Tile M=128(C) x N=64, 256 thr (4 waves, wave tile 64x32), 512 blocks, 2/CU.
// A = XMT bf16 via global_load_lds (inverse-swizzled source, linear dest).
// B = fp32 E slab (64 rows x 64 cols/tile), reg -> bf16 -> swizzled LDS.
__global__ __launch_bounds__(256, 2) void gemm1_p(const unsigned short* __restrict__ XMT,
                                                  const float* __restrict__ E,
                                                  float* __restrict__ P1) {
    __shared__ __align__(16) unsigned short ldsA[2][128 * BK];  // 32 KB
    __shared__ __align__(16) unsigned short ldsB[2][64 * BK];   // 16 KB
    const int bx = blockIdx.x;
    const int ks = bx >> 7;            // high bits: same-XCD neighbors share panel
    const int n0 = (bx & 127) * 64;
    const int kb = ks * KCH;
    const int t = threadIdx.x;
    const int w = t >> 6, lane = t & 63, q = lane >> 4, l15 = lane & 15;
    const int wm = (w & 1) * 64, wn = (w >> 1) * 32;
    // A gload map: inst (i,w): rows i*32+w*8+lr, slot lane&7, src chunk (lane&7)^lr
    const int lr = lane >> 3;
    const int lch = (lane & 7) ^ lr;
    // E staging: thread owns rows vg*4+u (u<4), cols jc*4..+3
    const int jc = t & 15;
    const int vg = t >> 4;

    floatx4 acc[4][2] = {};
    float4 er0[4], er1[4];

#define G1_GLOADA(TI, BUF)                                                          \
    {                                                                               \
        const int kk_ = kb + (TI) * BK;                                             \
        _Pragma("unroll")                                                           \
        for (int i = 0; i < 4; ++i)                                                 \
            gload16(&XMT[(size_t)(i * 32 + w * 8 + lr) * V + kk_ + 8 * lch],        \
                    &ldsA[BUF][i * 2048 + w * 512]);                                \
    }
#define G1_ELOAD(ER, TI)                                                            \
    {                                                                               \
        const int kk_ = kb + (TI) * BK;                                             \
        _Pragma("unroll")                                                           \
        for (int u = 0; u < 4; ++u)                                                 \
            ER[u] = *(const float4*)&E[(size_t)(kk_ + vg * 4 + u) * V + n0 + jc * 4]; \
    }
#define G1_CONV(ER, BUF)                                                            \
    {                                                                               \
        _Pragma("unroll")                                                           \
        for (int jj = 0; jj < 4; ++jj) {                                            \
            const int j = jc * 4 + jj;                                              \
            ushort4 b;                                                              \
            b.x = f2bf(ER[0][jj]); b.y = f2bf(ER[1][jj]);                           \
            b.z = f2bf(ER[2][jj]); b.w = f2bf(ER[3][jj]);                           \
            *(ushort4*)&ldsB[BUF][j * BK + ((vg >> 1) ^ (j & 7)) * 8 + (vg & 1) * 4] = b; \
        }                                                                           \
    }
#define G1_MFMA(pA, pB)                                                             \
    {                                                                               \
        _Pragma("unroll")                                                           \
        for (int kk = 0; kk < BK; kk += 32) {                                       \
            short8 af[4], bfv[2];                                                   \
            _Pragma("unroll")                                                       \
            for (int mi = 0; mi < 4; ++mi) {                                        \
                const int m = wm + mi * 16 + l15;                                   \
                af[mi] = *(const short8*)&pA[m * BK + 8 * (((kk >> 3) + q) ^ (m & 7))]; \
            }                                                                       \
            _Pragma("unroll")                                                       \
            for (int ni = 0; ni < 2; ++ni) {                                        \
                const int n = wn + ni * 16 + l15;                                   \
                bfv[ni] = *(const short8*)&pB[n * BK + 8 * (((kk >> 3) + q) ^ (n & 7))]; \
            }                                                                       \
            _Pragma("unroll")                                                       \
            for (int mi = 0; mi < 4; ++mi)                                          \
                _Pragma("unroll")                                                   \
                for (int ni = 0; ni < 2; ++ni)                                      \
                    acc[mi][ni] = __builtin_amdgcn_mfma_f32_16x16x32_bf16(          \
                        af[mi], bfv[ni], acc[mi][ni], 0, 0, 0);                     \
        }                                                                           \
    }

    // prologue: tile 0 staged, E(1) in regs
    G1_ELOAD(er0, 0);
    G1_GLOADA(0, 0);
    G1_ELOAD(er1, 1);
    G1_CONV(er0, 0);
    SWAIT("vmcnt(4) lgkmcnt(0)");   // retire the 4 gload_lds; er1 rides
    SBAR();
    SFENCE();

#define G1_BODY(T, PF_ER, CV_ER)                                                    \
    {                                                                               \
        const int t1 = (T) + 1;                                                     \
        const int t2 = ((T) + 2 < NI) ? (T) + 2 : NI - 1;                           \
        const bool pf = t1 < NI;                                                    \
        if (pf) {                                                                   \
            G1_GLOADA(t1, cur ^ 1);                                                 \
            G1_ELOAD(PF_ER, t2);                                                    \
        }                                                                           \
        SFENCE();                                                                   \
        __builtin_amdgcn_s_setprio(1);                                              \
        G1_MFMA((&ldsA[cur][0]), (&ldsB[cur][0]));                                  \
        __builtin_amdgcn_s_setprio(0);                                              \
        SFENCE();                                                                   \
        if (pf) {                                                                   \
            G1_CONV(CV_ER, cur ^ 1);                                                \
            SWAIT("vmcnt(4) lgkmcnt(0)");                                           \
            SBAR();                                                                 \
            SFENCE();                                                               \
            cur ^= 1;                                                               \
        }                                                                           \
    }

    int cur = 0;
    for (int tt = 0; tt < NI; tt += 2) {
        G1_BODY(tt, er0, er1);
        G1_BODY(tt + 1, er1, er0);
    }
#undef G1_BODY
#undef G1_MFMA
#undef G1_CONV
#undef G1_ELOAD
#undef G1_GLOADA

    float* Pks = P1 + (size_t)ks * C * V;
#pragma unroll
    for (int mi = 0; mi < 4; ++mi) {
        int mrow = wm + mi * 16 + q * 4;
#pragma unroll
        for (int ni = 0; ni < 2; ++ni) {
            int n = n0 + wn + ni * 16 + l15;
#pragma unroll
            for (int r = 0; r < 4; ++r)
                Pks[(size_t)(mrow + r) * V + n] = acc[mi][ni][r];
        }
    }
}

// ---------------------------------------------------------------- GEMM2
// P2[ks][i][c] = sum_{j in chunk ks} E[i][j] * YT[c][j]
// Tile M=64 x N=128(C), 256 thr (wave tile 32x64), 512 blocks, 2/CU.
// A = fp32 E rows (256B contiguous/row), reg -> bf16 -> swizzled LDS.
// B = YT bf16 via global_load_lds.
__global__ __launch_bounds__(256, 2) void gemm2_p(const float* __restrict__ E,
                                                  const unsigned short* __restrict__ YT,
                                                  float* __restrict__ P2) {
    __shared__ __align__(16) unsigned short ldsA[2][64 * BK];   // 16 KB
    __shared__ __align__(16) unsigned short ldsB[2][128 * BK];  // 32 KB
    const int bx = blockIdx.x;
    const int ks = bx >> 7;
    const int m0 = (bx & 127) * 64;
    const int kb = ks * KCH;
    const int t = threadIdx.x;
    const int w = t >> 6, lane = t & 63, q = lane >> 4, l15 = lane & 15;
    const int wm = (w & 1) * 32, wn = (w >> 1) * 64;
    const int lr = lane >> 3;
    const int lch = (lane & 7) ^ lr;
    // E staging: thread owns rows arr+16u (u<4), 16B chunk ach of the 256B row seg
    const int ach = t & 15;
    const int arr = t >> 4;

    floatx4 acc[2][4] = {};
    float4 er0[4], er1[4];

#define G2_GLOADB(TI, BUF)                                                          \
    {                                                                               \
        const int kk_ = kb + (TI) * BK;                                             \
        _Pragma("unroll")                                                           \
        for (int i = 0; i < 4; ++i)                                                 \
            gload16(&YT[(size_t)(i * 32 + w * 8 + lr) * V + kk_ + 8 * lch],         \
                    &ldsB[BUF][i * 2048 + w * 512]);                                \
    }
#define G2_ELOAD(ER, TI)                                                            \
    {                                                                               \
        const int kk_ = kb + (TI) * BK;                                             \
        _Pragma("unroll")                                                           \
        for (int u = 0; u < 4; ++u)                                                 \
            ER[u] = *(const float4*)&E[(size_t)(m0 + arr + 16 * u) * V + kk_ + ach * 4]; \
    }
#define G2_CONV(ER, BUF)                                                            \
    {                                                                               \
        _Pragma("unroll")                                                           \
        for (int u = 0; u < 4; ++u) {                                               \
            const int row = arr + 16 * u;                                           \
            ushort4 av;                                                             \
            av.x = f2bf(ER[u].x); av.y = f2bf(ER[u].y);                             \
            av.z = f2bf(ER[u].z); av.w = f2bf(ER[u].w);                             \
            *(ushort4*)&ldsA[BUF][row * BK + ((ach >> 1) ^ (row & 7)) * 8 + (ach & 1) * 4] = av; \
        }                                                                           \
    }
#define G2_MFMA(pA, pB)                                                             \
    {                                                                               \
        _Pragma("unroll")                                                           \
        for (int kk = 0; kk < BK; kk += 32) {                                       \
            short8 af[2], bfv[4];                                                   \
            _Pragma("unroll")                                                       \
            for (int mi = 0; mi < 2; ++mi) {                                        \
                const int m = wm + mi * 16 + l15;                                   \
                af[mi] = *(const short8*)&pA[m * BK + 8 * (((kk >> 3) + q) ^ (m & 7))]; \
            }                                                                       \
            _Pragma("unroll")                                                       \
            for (int ni = 0; ni < 4; ++ni) {                                        \
                const int n = wn + ni * 16 + l15;                                   \
                bfv[ni] = *(const short8*)&pB[n * BK + 8 * (((kk >> 3) + q) ^ (n & 7))]; \
            }                                                                       \
            _Pragma("unroll")                                                       \
            for (int mi = 0; mi < 2; ++mi)                                          \
                _Pragma("unroll")                                                   \
                for (int ni = 0; ni < 4; ++ni)                                      \
                    acc[mi][ni] = __builtin_amdgcn_mfma_f32_16x16x32_bf16(          \
                        af[mi], bfv[ni], acc[mi][ni], 0, 0, 0);                     \
        }                                                                           \
    }

    // prologue
    G2_ELOAD(er0, 0);
    G2_GLOADB(0, 0);
    G2_ELOAD(er1, 1);
    G2_CONV(er0, 0);
    SWAIT("vmcnt(4) lgkmcnt(0)");   // retire gloads; er1 rides
    SBAR();
    SFENCE();

#define G2_BODY(T, PF_ER, CV_ER)                                                    \
    {                                                                               \
        const int t1 = (T) + 1;                                                     \
        const int t2 = ((T) + 2 < NI) ? (T) + 2 : NI - 1;                           \
        const bool pf = t1 < NI;                                                    \
        if (pf) {                                                                   \
            G2_GLOADB(t1, cur ^ 1);                                                 \
            G2_ELOAD(PF_ER, t2);                                                    \
        }                                                                           \
        SFENCE();                                                                   \
        __builtin_amdgcn_s_setprio(1);                                              \
        G2_MFMA((&ldsA[cur][0]), (&ldsB[cur][0]));                                  \
        __builtin_amdgcn_s_setprio(0);                                              \
        SFENCE();                                                                   \
        if (pf) {                                                                   \
            G2_CONV(CV_ER, cur ^ 1);                                                \
            SWAIT("vmcnt(4) lgkmcnt(0)");                                           \
            SBAR();                                                                 \
            SFENCE();                                                               \
            cur ^= 1;                                                               \
        }                                                                           \
    }

    int cur = 0;
    for (int tt = 0; tt < NI; tt += 2) {
        G2_BODY(tt, er0, er1);
        G2_BODY(tt + 1, er1, er0);
    }
#undef G2_BODY
#undef G2_MFMA
#undef G2_CONV
#undef G2_ELOAD
#undef G2_GLOADB

    float* Pks = P2 + (size_t)ks * V * C;
#pragma unroll
    for (int mi = 0; mi < 2; ++mi) {
        int mrow = m0 + wm + mi * 16 + q * 4;
#pragma unroll
        for (int ni = 0; ni < 4; ++ni) {
            int n = wn + ni * 16 + l15;
#pragma unroll
            for (int r = 0; r < 4; ++r)
                Pks[(size_t)(mrow + r) * C + n] = acc[mi][ni][r];
        }
    }
}

// ---------------------------------------------------------------- reductions
__global__ __launch_bounds__(256) void red1(const float* __restrict__ P1,
                                            const float* __restrict__ ev0,
                                            const float* __restrict__ ev1,
                                            const float* __restrict__ dt,
                                            unsigned short* __restrict__ YT) {
    int id = blockIdx.x * 256 + threadIdx.x;
    int c = id >> 10;
    int j0 = (id & 1023) * 8;
    float s[8] = {};
#pragma unroll
    for (int ks = 0; ks < KS; ++ks) {
        const float* row = &P1[((size_t)ks * C + c) * V + j0];
        float4 a = *(const float4*)row;
        float4 b = *(const float4*)(row + 4);
        s[0] += a.x; s[1] += a.y; s[2] += a.z; s[3] += a.w;
        s[4] += b.x; s[5] += b.y; s[6] += b.z; s[7] += b.w;
    }
    float t0 = dt[c], t1 = dt[C + c];
    float a0 = ev0[j0 >> 7] * t0;
    short8 yv;
#pragma unroll
    for (int jj = 0; jj < 8; ++jj) {
        float coef = __expf(-(a0 + ev1[(j0 + jj) & 127] * t1));
        yv[jj] = (short)f2bf(s[jj] * coef);
    }
    *(short8*)&YT[(size_t)c * V + j0] = yv;
}

__global__ __launch_bounds__(256) void red2(const float* __restrict__ P2,
                                            float* __restrict__ out) {
    int id = blockIdx.x * 256 + threadIdx.x;
    size_t off = (size_t)id * 4;
    float4 s = {0.f, 0.f, 0.f, 0.f};
#pragma unroll
    for (int ks = 0; ks < KS; ++ks) {
        float4 v = *(const float4*)&P2[(size_t)ks * V * C + off];
        s.x += v.x; s.y += v.y; s.z += v.z; s.w += v.w;
    }
    *(float4*)&out[off] = s;
}

// ---------------------------------------------------------------- launch
extern "C" void kernel_launch(void* const* d_in, const int* in_sizes, int n_in,
                              void* d_out, int out_size, void* d_ws, size_t ws_size,
                              hipStream_t stream) {
    const float* x    = (const float*)d_in[0];
    const float* mass = (const float*)d_in[3];
    const float* ev0  = (const float*)d_in[4];
    const float* ev1  = (const float*)d_in[5];
    const float* E    = (const float*)d_in[6];
    const float* dt   = (const float*)d_in[7];
    float* out = (float*)d_out;

    // ws: XMT (2 MB) | YT (2 MB) | P (16 MB, reused by both GEMMs)
    unsigned short* XMT = (unsigned short*)d_ws;
    unsigned short* YT  = XMT + (size_t)V * C;
    float* P = (float*)(YT + (size_t)V * C);

    prep_xmt<<<dim3(V / 64, C / 64), 256, 0, stream>>>(x, mass, XMT);
    gemm1_p<<<(V / 64) * KS, 256, 0, stream>>>(XMT, E, P);
    red1<<<(C * V / 8) / 256, 256, 0, stream>>>(P, ev0, ev1, dt, YT);
    gemm2_p<<<(V / 64) * KS, 256, 0, stream>>>(E, YT, P);
    red2<<<(V * C / 4) / 256, 256, 0, stream>>>(P, out);
}